// Round 1
// baseline (101.041 us; speedup 1.0000x reference)
//
#include <hip/hip_runtime.h>
#include <math.h>

// NCC loss, restructured:
//   sum(cross)  = A - D/225,  A = sum I*J*cnt,  D = sum S_I*S_J
//   sum(I_var)  = B - E/225,  B = sum I*I*cnt,  E = sum S_I^2
//   sum(J_var)  = C - F/225,  C = sum J*J*cnt,  F = sum S_J^2
// where S_X = 15x15 zero-padded box sum of X, cnt(i,j) = ch(i)*cw(j),
// ch(i) = min(i,7)+min(511-i,7)+1.  Only TWO box filters needed.

#define IMG_H 512
#define IMG_W 512
#define NB    16
#define TILE  32
#define HALO  7
#define SPAN  46            // TILE + 2*HALO
#define LSTR  47            // odd stride -> conflict-free column walks
#define VSTR  49            // odd stride -> conflict-free column walks
#define NTX   16
#define NTY   16
#define NBLK  (NB * NTX * NTY)   // 4096

__device__ __forceinline__ float winw(int i) {
    // number of 15-windows (zero-padded, stride 1) containing index i
    int a = i < 7 ? i : 7;
    int b = (511 - i) < 7 ? (511 - i) : 7;
    return (float)(a + b + 1);
}

__global__ __launch_bounds__(256) void ncc_main(const float* __restrict__ I,
                                                const float* __restrict__ J,
                                                float* __restrict__ partials) {
    __shared__ float lI[SPAN * LSTR];
    __shared__ float lJ[SPAN * LSTR];
    __shared__ float vI[TILE * VSTR];
    __shared__ float vJ[TILE * VSTR];
    __shared__ float red[4 * 6];

    const int tid = threadIdx.x;
    const int tx = blockIdx.x, ty = blockIdx.y, bz = blockIdx.z;
    const int R0 = ty * TILE - HALO;
    const int C0 = tx * TILE - HALO;
    const float* Ib = I + (size_t)bz * IMG_H * IMG_W;
    const float* Jb = J + (size_t)bz * IMG_H * IMG_W;

    // ---- stage 1: load 46x46 halo'd tile (zero-padded) into LDS ----
    for (int k = tid; k < SPAN * SPAN; k += 256) {
        int r = k / SPAN;
        int c = k - r * SPAN;
        int gr = R0 + r, gc = C0 + c;
        float iv = 0.0f, jv = 0.0f;
        if (gr >= 0 && gr < IMG_H && gc >= 0 && gc < IMG_W) {
            int gidx = gr * IMG_W + gc;
            iv = Ib[gidx];
            jv = Jb[gidx];
        }
        lI[r * LSTR + c] = iv;
        lJ[r * LSTR + c] = jv;
    }
    __syncthreads();

    // ---- stage 2: vertical 15-tap sliding sums -> vI/vJ[32][46] ----
    // thread -> (column c in 0..45, row-chunk of 8); 184 of 256 active
    {
        int c = tid % SPAN;
        int chunk = tid / SPAN;
        if (chunk < 4) {
            int r0 = chunk * 8;
            float sI = 0.0f, sJ = 0.0f;
            #pragma unroll
            for (int dr = 0; dr < 15; ++dr) {
                sI += lI[(r0 + dr) * LSTR + c];
                sJ += lJ[(r0 + dr) * LSTR + c];
            }
            vI[r0 * VSTR + c] = sI;
            vJ[r0 * VSTR + c] = sJ;
            #pragma unroll
            for (int r = 1; r < 8; ++r) {
                int rr = r0 + r;
                sI += lI[(rr + 14) * LSTR + c] - lI[(rr - 1) * LSTR + c];
                sJ += lJ[(rr + 14) * LSTR + c] - lJ[(rr - 1) * LSTR + c];
                vI[rr * VSTR + c] = sI;
                vJ[rr * VSTR + c] = sJ;
            }
        }
    }
    __syncthreads();

    // ---- stage 3: horizontal sliding sums + all six accumulations ----
    float acc0 = 0.f, acc1 = 0.f, acc2 = 0.f, acc3 = 0.f, acc4 = 0.f, acc5 = 0.f;
    {
        int r = tid & 31;        // output row in tile
        int chunk = tid >> 5;    // 0..7, 4 output cols each
        int c0 = chunk * 4;
        float sI = 0.0f, sJ = 0.0f;
        #pragma unroll
        for (int dc = 0; dc < 15; ++dc) {
            sI += vI[r * VSTR + c0 + dc];
            sJ += vJ[r * VSTR + c0 + dc];
        }
        float chw = winw(ty * TILE + r);
        #pragma unroll
        for (int i = 0; i < 4; ++i) {
            int c = c0 + i;
            if (i > 0) {
                sI += vI[r * VSTR + c + 14] - vI[r * VSTR + c - 1];
                sJ += vJ[r * VSTR + c + 14] - vJ[r * VSTR + c - 1];
            }
            acc3 += sI * sJ;
            acc4 += sI * sI;
            acc5 += sJ * sJ;
            float iv = lI[(r + HALO) * LSTR + c + HALO];
            float jv = lJ[(r + HALO) * LSTR + c + HALO];
            float w = chw * winw(tx * TILE + c);
            acc0 += iv * jv * w;
            acc1 += iv * iv * w;
            acc2 += jv * jv * w;
        }
    }

    // ---- block reduction: wave shuffle then LDS across the 4 waves ----
    float vals[6] = {acc0, acc1, acc2, acc3, acc4, acc5};
    #pragma unroll
    for (int k = 0; k < 6; ++k) {
        float v = vals[k];
        #pragma unroll
        for (int off = 32; off > 0; off >>= 1) v += __shfl_down(v, off, 64);
        vals[k] = v;
    }
    int wave = tid >> 6, lane = tid & 63;
    if (lane == 0) {
        #pragma unroll
        for (int k = 0; k < 6; ++k) red[wave * 6 + k] = vals[k];
    }
    __syncthreads();
    if (tid == 0) {
        int bidx = (bz * NTY + ty) * NTX + tx;
        #pragma unroll
        for (int k = 0; k < 6; ++k) {
            partials[bidx * 6 + k] = red[k] + red[6 + k] + red[12 + k] + red[18 + k];
        }
    }
}

__global__ __launch_bounds__(256) void ncc_finalize(const float* __restrict__ partials,
                                                    float* __restrict__ out) {
    __shared__ double red[4 * 6];
    int tid = threadIdx.x;
    double acc[6] = {0, 0, 0, 0, 0, 0};
    for (int b = tid; b < NBLK; b += 256) {
        #pragma unroll
        for (int k = 0; k < 6; ++k) acc[k] += (double)partials[b * 6 + k];
    }
    #pragma unroll
    for (int k = 0; k < 6; ++k) {
        double v = acc[k];
        #pragma unroll
        for (int off = 32; off > 0; off >>= 1) v += __shfl_down(v, off, 64);
        acc[k] = v;
    }
    int wave = tid >> 6, lane = tid & 63;
    if (lane == 0) {
        #pragma unroll
        for (int k = 0; k < 6; ++k) red[wave * 6 + k] = acc[k];
    }
    __syncthreads();
    if (tid == 0) {
        double s[6];
        #pragma unroll
        for (int k = 0; k < 6; ++k) s[k] = red[k] + red[6 + k] + red[12 + k] + red[18 + k];
        double A = s[0], Bv = s[1], Cv = s[2], D = s[3], E = s[4], F = s[5];
        double num = A - D / 225.0;
        double varI = Bv - E / 225.0;
        double varJ = Cv - F / 225.0;
        double cc = num / sqrt(varI * varJ);
        out[0] = (float)(-cc);
    }
}

extern "C" void kernel_launch(void* const* d_in, const int* in_sizes, int n_in,
                              void* d_out, int out_size, void* d_ws, size_t ws_size,
                              hipStream_t stream) {
    const float* I = (const float*)d_in[0];
    const float* J = (const float*)d_in[1];
    float* partials = (float*)d_ws;   // NBLK*6 floats = 96 KB

    dim3 grid(NTX, NTY, NB);
    ncc_main<<<grid, 256, 0, stream>>>(I, J, partials);
    ncc_finalize<<<1, 256, 0, stream>>>(partials, (float*)d_out);
}

// Round 2
// 99.641 us; speedup vs baseline: 1.0141x; 1.0141x over previous
//
#include <hip/hip_runtime.h>
#include <math.h>

// NCC loss, restructured:
//   sum(cross)  = A - D/225,  A = sum I*J*cnt,  D = sum S_I*S_J
//   sum(I_var)  = B - E/225,  B = sum I*I*cnt,  E = sum S_I^2
//   sum(J_var)  = C - F/225,  C = sum J*J*cnt,  F = sum S_J^2
// where S_X = 15x15 zero-padded box sum of X, cnt(i,j) = ch(i)*cw(j),
// ch(i) = min(i,7)+min(511-i,7)+1.  Only TWO box filters needed.
//
// R2: 64x32 tiles (halo factor 2.07->1.75), A/B/C accumulated at load time
// from registers (no LDS center re-reads), stage-3 8-col register sliding.

#define IMG_H 512
#define IMG_W 512
#define NB    16
#define TW    64
#define TH    32
#define HALO  7
#define SPAN_R 46           // TH + 14
#define SPAN_C 78           // TW + 14
#define LSTR  78            // all lI/lJ accesses are row-contiguous across lanes
#define VSTR  79            // odd stride -> conflict-free for stage-3 row-varying lanes
#define NTX   8             // 512/64
#define NTY   16            // 512/32
#define NBLK  (NB * NTX * NTY)   // 2048

__device__ __forceinline__ float winw(int i) {
    int a = i < 7 ? i : 7;
    int b = (511 - i) < 7 ? (511 - i) : 7;
    return (float)(a + b + 1);
}

__global__ __launch_bounds__(256) void ncc_main(const float* __restrict__ I,
                                                const float* __restrict__ J,
                                                float* __restrict__ partials) {
    __shared__ float lI[SPAN_R * LSTR];
    __shared__ float lJ[SPAN_R * LSTR];
    __shared__ float vI[TH * VSTR];
    __shared__ float vJ[TH * VSTR];
    __shared__ float red[4 * 6];

    const int tid = threadIdx.x;
    const int tx = blockIdx.x, ty = blockIdx.y, bz = blockIdx.z;
    const int R0 = ty * TH - HALO;
    const int C0 = tx * TW - HALO;
    const float* Ib = I + (size_t)bz * IMG_H * IMG_W;
    const float* Jb = J + (size_t)bz * IMG_H * IMG_W;

    float a0 = 0.f, a1 = 0.f, a2 = 0.f;

    // ---- stage 1: load 46x78 halo'd tile (zero-padded) into LDS.
    // While loading, accumulate the raw weighted sums A,B,C over the
    // interior 32x64 pixels straight from registers (interior is always
    // in-bounds, and interiors don't overlap across blocks).
    for (int k = tid; k < SPAN_R * SPAN_C; k += 256) {
        int r = k / SPAN_C;
        int c = k - r * SPAN_C;
        int gr = R0 + r, gc = C0 + c;
        float iv = 0.0f, jv = 0.0f;
        if ((unsigned)gr < (unsigned)IMG_H && (unsigned)gc < (unsigned)IMG_W) {
            int gidx = gr * IMG_W + gc;
            iv = Ib[gidx];
            jv = Jb[gidx];
        }
        lI[r * LSTR + c] = iv;
        lJ[r * LSTR + c] = jv;
        if (r >= HALO && r < HALO + TH && c >= HALO && c < HALO + TW) {
            float w = winw(gr) * winw(gc);
            a0 += iv * jv * w;
            a1 += iv * iv * w;
            a2 += jv * jv * w;
        }
    }
    __syncthreads();

    // ---- stage 2: vertical 15-tap sliding sums -> vI/vJ[32][78] ----
    // 78 columns x 3 row-chunks (rows 11/11/10); 234 of 256 threads active
    {
        int cid = tid % SPAN_C;
        int chunk = tid / SPAN_C;
        if (chunk < 3) {
            int r0 = chunk * 11;
            int nr = (chunk == 2) ? 10 : 11;
            float sI = 0.0f, sJ = 0.0f;
            #pragma unroll
            for (int dr = 0; dr < 15; ++dr) {
                sI += lI[(r0 + dr) * LSTR + cid];
                sJ += lJ[(r0 + dr) * LSTR + cid];
            }
            vI[r0 * VSTR + cid] = sI;
            vJ[r0 * VSTR + cid] = sJ;
            for (int r = r0 + 1; r < r0 + nr; ++r) {
                sI += lI[(r + 14) * LSTR + cid] - lI[(r - 1) * LSTR + cid];
                sJ += lJ[(r + 14) * LSTR + cid] - lJ[(r - 1) * LSTR + cid];
                vI[r * VSTR + cid] = sI;
                vJ[r * VSTR + cid] = sJ;
            }
        }
    }
    __syncthreads();

    // ---- stage 3: horizontal sliding over an 8-col run per thread ----
    float a3 = 0.f, a4 = 0.f, a5 = 0.f;
    {
        int r = tid & 31;        // output row in tile
        int ch = tid >> 5;       // 0..7 -> 8 output cols each
        int c0 = ch * 8;
        int base = r * VSTR + c0;
        float va[22], vb[22];
        #pragma unroll
        for (int i = 0; i < 22; ++i) {
            va[i] = vI[base + i];
            vb[i] = vJ[base + i];
        }
        float sI = 0.0f, sJ = 0.0f;
        #pragma unroll
        for (int i = 0; i < 15; ++i) { sI += va[i]; sJ += vb[i]; }
        a3 += sI * sJ;
        a4 += sI * sI;
        a5 += sJ * sJ;
        #pragma unroll
        for (int i = 1; i < 8; ++i) {
            sI += va[i + 14] - va[i - 1];
            sJ += vb[i + 14] - vb[i - 1];
            a3 += sI * sJ;
            a4 += sI * sI;
            a5 += sJ * sJ;
        }
    }

    // ---- block reduction: wave shuffle then LDS across the 4 waves ----
    float vals[6] = {a0, a1, a2, a3, a4, a5};
    #pragma unroll
    for (int k = 0; k < 6; ++k) {
        float v = vals[k];
        #pragma unroll
        for (int off = 32; off > 0; off >>= 1) v += __shfl_down(v, off, 64);
        vals[k] = v;
    }
    int wave = tid >> 6, lane = tid & 63;
    if (lane == 0) {
        #pragma unroll
        for (int k = 0; k < 6; ++k) red[wave * 6 + k] = vals[k];
    }
    __syncthreads();
    if (tid == 0) {
        int bidx = (bz * NTY + ty) * NTX + tx;
        #pragma unroll
        for (int k = 0; k < 6; ++k) {
            partials[bidx * 6 + k] = red[k] + red[6 + k] + red[12 + k] + red[18 + k];
        }
    }
}

__global__ __launch_bounds__(256) void ncc_finalize(const float* __restrict__ partials,
                                                    float* __restrict__ out) {
    __shared__ double red[4 * 6];
    int tid = threadIdx.x;
    double acc[6] = {0, 0, 0, 0, 0, 0};
    for (int b = tid; b < NBLK; b += 256) {
        #pragma unroll
        for (int k = 0; k < 6; ++k) acc[k] += (double)partials[b * 6 + k];
    }
    #pragma unroll
    for (int k = 0; k < 6; ++k) {
        double v = acc[k];
        #pragma unroll
        for (int off = 32; off > 0; off >>= 1) v += __shfl_down(v, off, 64);
        acc[k] = v;
    }
    int wave = tid >> 6, lane = tid & 63;
    if (lane == 0) {
        #pragma unroll
        for (int k = 0; k < 6; ++k) red[wave * 6 + k] = acc[k];
    }
    __syncthreads();
    if (tid == 0) {
        double s[6];
        #pragma unroll
        for (int k = 0; k < 6; ++k) s[k] = red[k] + red[6 + k] + red[12 + k] + red[18 + k];
        double A = s[0], Bv = s[1], Cv = s[2], D = s[3], E = s[4], F = s[5];
        double num = A - D / 225.0;
        double varI = Bv - E / 225.0;
        double varJ = Cv - F / 225.0;
        double cc = num / sqrt(varI * varJ);
        out[0] = (float)(-cc);
    }
}

extern "C" void kernel_launch(void* const* d_in, const int* in_sizes, int n_in,
                              void* d_out, int out_size, void* d_ws, size_t ws_size,
                              hipStream_t stream) {
    const float* I = (const float*)d_in[0];
    const float* J = (const float*)d_in[1];
    float* partials = (float*)d_ws;   // NBLK*6 floats = 48 KB

    dim3 grid(NTX, NTY, NB);
    ncc_main<<<grid, 256, 0, stream>>>(I, J, partials);
    ncc_finalize<<<1, 256, 0, stream>>>(partials, (float*)d_out);
}

// Round 3
// 90.783 us; speedup vs baseline: 1.1130x; 1.0976x over previous
//
#include <hip/hip_runtime.h>
#include <math.h>

// NCC loss, restructured:
//   sum(cross)  = A - D/225,  A = sum I*J*cnt,  D = sum S_I*S_J
//   sum(I_var)  = B - E/225,  B = sum I*I*cnt,  E = sum S_I^2
//   sum(J_var)  = C - F/225,  C = sum J*J*cnt,  F = sum S_J^2
// where S_X = 15x15 zero-padded box sum of X, cnt(i,j) = ch(i)*cw(j),
// ch(i) = min(i,7)+min(511-i,7)+1.  Only TWO box filters needed.
//
// R3: fully vectorized LDS/global traffic.
//  - stage1: image-aligned 46x80 tile, float4 global loads + b128 LDS stores,
//    whole-quad validity (W%4==0), A/B/C accumulated from registers.
//  - stage2: column-pair threads, all b64 LDS reads/writes.
//  - stage3: b32+10*b64+b32 reads, VSTR=82 (gcd(41,32)=1 -> conflict-free).

#define IMG_H 512
#define IMG_W 512
#define NB    16
#define TW    64
#define TH    32
#define HALO  7
#define SPAN_R 46           // TH + 14
#define SPAN_C 80           // TW + 16 (aligned halo: C0 = tx*64 - 8)
#define LSTR  80
#define VSTR  82            // odd-granule stride for conflict-free stage-3 b64
#define NTX   8             // 512/64
#define NTY   16            // 512/32
#define NBLK  (NB * NTX * NTY)   // 2048

__device__ __forceinline__ float winw(int i) {
    int a = i < 7 ? i : 7;
    int b = (511 - i) < 7 ? (511 - i) : 7;
    return (float)(a + b + 1);
}

__global__ __launch_bounds__(256) void ncc_main(const float* __restrict__ I,
                                                const float* __restrict__ J,
                                                float* __restrict__ partials) {
    __shared__ float lI[SPAN_R * LSTR];
    __shared__ float lJ[SPAN_R * LSTR];
    __shared__ float vI[TH * VSTR];
    __shared__ float vJ[TH * VSTR];
    __shared__ float red[4 * 6];

    const int tid = threadIdx.x;
    const int tx = blockIdx.x, ty = blockIdx.y, bz = blockIdx.z;
    const int R0 = ty * TH - HALO;
    const int C0 = tx * TW - 8;          // aligned halo start (stored col 0)
    const float* Ib = I + (size_t)bz * IMG_H * IMG_W;
    const float* Jb = J + (size_t)bz * IMG_H * IMG_W;

    float a0 = 0.f, a1 = 0.f, a2 = 0.f;

    // ---- stage 1: 46x80 tile, float4 loads, b128 LDS stores ----
    // 46 rows x 20 quads = 920 float4 per array.
    for (int k = tid; k < SPAN_R * (SPAN_C / 4); k += 256) {
        int r = k / (SPAN_C / 4);
        int q = k - r * (SPAN_C / 4);
        int gr = R0 + r;
        int gc4 = C0 + q * 4;
        float4 iv = make_float4(0.f, 0.f, 0.f, 0.f);
        float4 jv = make_float4(0.f, 0.f, 0.f, 0.f);
        if ((unsigned)gr < (unsigned)IMG_H && (unsigned)gc4 < (unsigned)IMG_W) {
            const float4* ip = reinterpret_cast<const float4*>(Ib + gr * IMG_W + gc4);
            const float4* jp = reinterpret_cast<const float4*>(Jb + gr * IMG_W + gc4);
            iv = *ip;
            jv = *jp;
        }
        reinterpret_cast<float4*>(lI)[r * (LSTR / 4) + q] = iv;
        reinterpret_cast<float4*>(lJ)[r * (LSTR / 4) + q] = jv;
        // interior pixels: stored rows 7..38, stored quads 2..17 (cols 8..71)
        if (r >= HALO && r < HALO + TH && q >= 2 && q < 18) {
            float wr = winw(gr);
            float w0 = wr * winw(gc4 + 0);
            float w1 = wr * winw(gc4 + 1);
            float w2 = wr * winw(gc4 + 2);
            float w3 = wr * winw(gc4 + 3);
            a0 += iv.x * jv.x * w0 + iv.y * jv.y * w1 + iv.z * jv.z * w2 + iv.w * jv.w * w3;
            a1 += iv.x * iv.x * w0 + iv.y * iv.y * w1 + iv.z * iv.z * w2 + iv.w * iv.w * w3;
            a2 += jv.x * jv.x * w0 + jv.y * jv.y * w1 + jv.z * jv.z * w2 + jv.w * jv.w * w3;
        }
    }
    __syncthreads();

    // ---- stage 2: vertical 15-tap sliding sums, column-pair threads, b64 ----
    // 40 pairs x 6 row-chunks (rows 6,6,6,6,4,4); 240 of 256 threads active.
    {
        int p = tid % 40;
        int chunk = tid / 40;
        if (chunk < 6) {
            int r0 = (chunk < 4) ? chunk * 6 : 24 + (chunk - 4) * 4;
            int nr = (chunk < 4) ? 6 : 4;
            const float2* lI2 = reinterpret_cast<const float2*>(lI);
            const float2* lJ2 = reinterpret_cast<const float2*>(lJ);
            float2* vI2 = reinterpret_cast<float2*>(vI);
            float2* vJ2 = reinterpret_cast<float2*>(vJ);
            float2 sI = make_float2(0.f, 0.f), sJ = make_float2(0.f, 0.f);
            #pragma unroll
            for (int dr = 0; dr < 15; ++dr) {
                float2 i2 = lI2[(r0 + dr) * 40 + p];
                float2 j2 = lJ2[(r0 + dr) * 40 + p];
                sI.x += i2.x; sI.y += i2.y;
                sJ.x += j2.x; sJ.y += j2.y;
            }
            vI2[r0 * 41 + p] = sI;
            vJ2[r0 * 41 + p] = sJ;
            for (int r = r0 + 1; r < r0 + nr; ++r) {
                float2 iA = lI2[(r + 14) * 40 + p], iB = lI2[(r - 1) * 40 + p];
                float2 jA = lJ2[(r + 14) * 40 + p], jB = lJ2[(r - 1) * 40 + p];
                sI.x += iA.x - iB.x; sI.y += iA.y - iB.y;
                sJ.x += jA.x - jB.x; sJ.y += jA.y - jB.y;
                vI2[r * 41 + p] = sI;
                vJ2[r * 41 + p] = sJ;
            }
        }
    }
    __syncthreads();

    // ---- stage 3: horizontal sliding over an 8-col run per thread ----
    // v at stored col s corresponds to "needed" col s-1; output col c uses
    // needed cols c..c+14 = stored cols c+1..c+15.
    float a3 = 0.f, a4 = 0.f, a5 = 0.f;
    {
        int r = tid & 31;        // output row in tile
        int ch = tid >> 5;       // 0..7 -> 8 output cols each
        int c0 = ch * 8;
        int base = r * VSTR + c0;        // stored-col origin (even)
        const float2* vI2 = reinterpret_cast<const float2*>(vI);
        const float2* vJ2 = reinterpret_cast<const float2*>(vJ);
        float va[22], vb[22];
        va[0] = vI[base + 1];  vb[0] = vJ[base + 1];
        #pragma unroll
        for (int i = 0; i < 10; ++i) {
            float2 x = vI2[(base + 2) / 2 + i];
            float2 y = vJ2[(base + 2) / 2 + i];
            va[1 + 2 * i] = x.x; va[2 + 2 * i] = x.y;
            vb[1 + 2 * i] = y.x; vb[2 + 2 * i] = y.y;
        }
        va[21] = vI[base + 22]; vb[21] = vJ[base + 22];

        float sI = 0.0f, sJ = 0.0f;
        #pragma unroll
        for (int i = 0; i < 15; ++i) { sI += va[i]; sJ += vb[i]; }
        a3 += sI * sJ;
        a4 += sI * sI;
        a5 += sJ * sJ;
        #pragma unroll
        for (int i = 1; i < 8; ++i) {
            sI += va[i + 14] - va[i - 1];
            sJ += vb[i + 14] - vb[i - 1];
            a3 += sI * sJ;
            a4 += sI * sI;
            a5 += sJ * sJ;
        }
    }

    // ---- block reduction: wave shuffle then LDS across the 4 waves ----
    float vals[6] = {a0, a1, a2, a3, a4, a5};
    #pragma unroll
    for (int k = 0; k < 6; ++k) {
        float v = vals[k];
        #pragma unroll
        for (int off = 32; off > 0; off >>= 1) v += __shfl_down(v, off, 64);
        vals[k] = v;
    }
    int wave = tid >> 6, lane = tid & 63;
    if (lane == 0) {
        #pragma unroll
        for (int k = 0; k < 6; ++k) red[wave * 6 + k] = vals[k];
    }
    __syncthreads();
    if (tid == 0) {
        int bidx = (bz * NTY + ty) * NTX + tx;
        #pragma unroll
        for (int k = 0; k < 6; ++k) {
            partials[bidx * 6 + k] = red[k] + red[6 + k] + red[12 + k] + red[18 + k];
        }
    }
}

__global__ __launch_bounds__(256) void ncc_finalize(const float* __restrict__ partials,
                                                    float* __restrict__ out) {
    __shared__ double red[4 * 6];
    int tid = threadIdx.x;
    double acc[6] = {0, 0, 0, 0, 0, 0};
    for (int b = tid; b < NBLK; b += 256) {
        #pragma unroll
        for (int k = 0; k < 6; ++k) acc[k] += (double)partials[b * 6 + k];
    }
    #pragma unroll
    for (int k = 0; k < 6; ++k) {
        double v = acc[k];
        #pragma unroll
        for (int off = 32; off > 0; off >>= 1) v += __shfl_down(v, off, 64);
        acc[k] = v;
    }
    int wave = tid >> 6, lane = tid & 63;
    if (lane == 0) {
        #pragma unroll
        for (int k = 0; k < 6; ++k) red[wave * 6 + k] = acc[k];
    }
    __syncthreads();
    if (tid == 0) {
        double s[6];
        #pragma unroll
        for (int k = 0; k < 6; ++k) s[k] = red[k] + red[6 + k] + red[12 + k] + red[18 + k];
        double A = s[0], Bv = s[1], Cv = s[2], D = s[3], E = s[4], F = s[5];
        double num = A - D / 225.0;
        double varI = Bv - E / 225.0;
        double varJ = Cv - F / 225.0;
        double cc = num / sqrt(varI * varJ);
        out[0] = (float)(-cc);
    }
}

extern "C" void kernel_launch(void* const* d_in, const int* in_sizes, int n_in,
                              void* d_out, int out_size, void* d_ws, size_t ws_size,
                              hipStream_t stream) {
    const float* I = (const float*)d_in[0];
    const float* J = (const float*)d_in[1];
    float* partials = (float*)d_ws;   // NBLK*6 floats = 48 KB

    dim3 grid(NTX, NTY, NB);
    ncc_main<<<grid, 256, 0, stream>>>(I, J, partials);
    ncc_finalize<<<1, 256, 0, stream>>>(partials, (float*)d_out);
}